// Round 3
// baseline (688.156 us; speedup 1.0000x reference)
//
#include <hip/hip_runtime.h>

typedef unsigned short ushort_t;
typedef __attribute__((ext_vector_type(8))) __bf16 bf16x8;
typedef __attribute__((ext_vector_type(4))) float f32x4;

constexpr int B_ = 8, N_ = 1025, C_ = 1024, H_ = 16, HD = 64;
constexpr int M_QKV = B_ * N_;          // 8200
constexpr int M_PROJ = 2 * B_ * N_;     // 16400
constexpr int K_ = 1024;
constexpr size_t S1 = (size_t)B_ * H_ * N_ * HD;   // per-tensor q/k/v elems = 8,396,800
constexpr size_t BNC = (size_t)B_ * N_ * C_;       // 8,396,800 (== S1)

__device__ __forceinline__ ushort_t f2bf(float f) {
    union { float f; unsigned u; } a; a.f = f;
    unsigned r = a.u + 0x7FFFu + ((a.u >> 16) & 1u);
    return (ushort_t)(r >> 16);
}

union U4 { uint4 v; ushort_t s[8]; };

__device__ __forceinline__ uint4 packbf8(float4 a, float4 b) {
    U4 u;
    u.s[0] = f2bf(a.x); u.s[1] = f2bf(a.y); u.s[2] = f2bf(a.z); u.s[3] = f2bf(a.w);
    u.s[4] = f2bf(b.x); u.s[5] = f2bf(b.y); u.s[6] = f2bf(b.z); u.s[7] = f2bf(b.w);
    return u.v;
}

// ---------------------------------------------------------------------------
// GEMM 1: QKV = X[M,K](f32) * Wqkv[3072,K](f32)^T -> scatter q/k/v [B,H,N,64] bf16
// ---------------------------------------------------------------------------
__global__ __launch_bounds__(256)
void gemm_qkv(const float* __restrict__ A, const float* __restrict__ Bm,
              ushort_t* __restrict__ q, ushort_t* __restrict__ k, ushort_t* __restrict__ v) {
    __shared__ ushort_t As[64][40];
    __shared__ ushort_t Bs[64][40];
    const int tid = threadIdx.x;
    const int wave = tid >> 6, lane = tid & 63;
    const int quad = lane >> 4, l16 = lane & 15;
    const int m0 = blockIdx.y * 64, n0 = blockIdx.x * 64;
    const int wm = (wave & 1) * 32, wn = (wave >> 1) * 32;
    const int lrow = tid >> 2;           // 0..63
    const int lcol = (tid & 3) * 8;      // 0,8,16,24

    f32x4 acc[2][2] = {};

    for (int k0 = 0; k0 < K_; k0 += 32) {
        float4 a0 = make_float4(0, 0, 0, 0), a1 = a0, b0, b1;
        const int arow = m0 + lrow;
        if (arow < M_QKV) {
            const float* ap = A + (size_t)arow * K_ + k0 + lcol;
            a0 = *(const float4*)ap; a1 = *(const float4*)(ap + 4);
        }
        const float* bp = Bm + (size_t)(n0 + lrow) * K_ + k0 + lcol;
        b0 = *(const float4*)bp; b1 = *(const float4*)(bp + 4);
        __syncthreads();
        *(uint4*)(&As[lrow][lcol]) = packbf8(a0, a1);
        *(uint4*)(&Bs[lrow][lcol]) = packbf8(b0, b1);
        __syncthreads();
        bf16x8 af[2], bfr[2];
#pragma unroll
        for (int i = 0; i < 2; i++) {
            af[i]  = *(const bf16x8*)(&As[wm + i * 16 + l16][quad * 8]);
            bfr[i] = *(const bf16x8*)(&Bs[wn + i * 16 + l16][quad * 8]);
        }
#pragma unroll
        for (int im = 0; im < 2; im++)
#pragma unroll
            for (int in = 0; in < 2; in++)
                acc[im][in] = __builtin_amdgcn_mfma_f32_16x16x32_bf16(af[im], bfr[in], acc[im][in], 0, 0, 0);
    }

    // epilogue: scatter to q/k/v in [B,H,N,64] (bf16)
#pragma unroll
    for (int im = 0; im < 2; im++) {
#pragma unroll
        for (int in = 0; in < 2; in++) {
            const int gcol = n0 + wn + in * 16 + l16;     // 0..3071
            const int which = gcol >> 10;                 // 0/1/2
            const int c = gcol & 1023;
            const int h = c >> 6, d = c & 63;
            ushort_t* dst = which == 0 ? q : (which == 1 ? k : v);
#pragma unroll
            for (int r = 0; r < 4; r++) {
                const int grow = m0 + wm + im * 16 + quad * 4 + r;
                if (grow < M_QKV) {
                    const int b = grow / N_;
                    const int nn = grow - b * N_;
                    dst[(((size_t)(b * H_ + h) * N_ + nn) * HD) + d] = f2bf(acc[im][in][r]);
                }
            }
        }
    }
}

// ---------------------------------------------------------------------------
// Attention: per (qtile, bh, path). path0: S=q·k^T -> x_ori. path1: S=v·v^T -> x_new
// q/k/v bf16 [B,H,N,64]; outputs bf16 [B,N,C]
// ---------------------------------------------------------------------------
__global__ __launch_bounds__(256)
void attn_kernel(const ushort_t* __restrict__ q, const ushort_t* __restrict__ k,
                 const ushort_t* __restrict__ v,
                 ushort_t* __restrict__ xvv, ushort_t* __restrict__ xori) {
    __shared__ ushort_t Ks[64][72];    // key-major: [key][dim]
    __shared__ ushort_t Vt[64][72];    // transposed: [dim][key]
    __shared__ ushort_t Ps[4][16][72]; // per-wave P: [row][key]

    const int tid = threadIdx.x;
    const int wave = tid >> 6, lane = tid & 63;
    const int quad = lane >> 4, l16 = lane & 15;
    const int bh = blockIdx.y;
    const int path = blockIdx.z;
    const int b = bh >> 4, h = bh & 15;

    const ushort_t* Qp = (path == 0) ? q : v;
    const ushort_t* Kp = (path == 0) ? k : v;
    ushort_t* outp = (path == 0) ? xori : xvv;

    const size_t base = (size_t)bh * N_ * HD;
    const int qr0 = blockIdx.x * 64 + wave * 16;
    const float NEG = -30000.0f;

    // load Q fragments (16 rows x 64 dims per wave)
    bf16x8 qf[2];
    {
        const int qrow = qr0 + l16;
#pragma unroll
        for (int kk = 0; kk < 2; kk++) {
            U4 u; u.v = make_uint4(0, 0, 0, 0);
            if (qrow < N_) u.v = *(const uint4*)(Qp + base + (size_t)qrow * HD + kk * 32 + quad * 8);
            qf[kk] = *(const bf16x8*)u.s;
        }
    }

    float m_r[4], l_r[4];
    f32x4 o[4] = {};
#pragma unroll
    for (int r = 0; r < 4; r++) { m_r[r] = NEG; l_r[r] = 0.f; }

    const int nkt = (N_ + 63) / 64;  // 17
    for (int kt = 0; kt < nkt; kt++) {
        const int key0 = kt * 64;
        __syncthreads();
        // stage K tile (row-major) and V tile (transposed)
#pragma unroll
        for (int i = 0; i < 2; i++) {
            const int c = tid + i * 256;       // 0..511
            const int row = c >> 3;            // key within tile
            const int cc = (c & 7) * 8;        // dim start
            const int key = key0 + row;
            U4 kv, vv;
            kv.v = make_uint4(0, 0, 0, 0);
            vv.v = make_uint4(0, 0, 0, 0);
            if (key < N_) {
                kv.v = *(const uint4*)(Kp + base + (size_t)key * HD + cc);
                vv.v = *(const uint4*)(v + base + (size_t)key * HD + cc);
            }
            *(uint4*)(&Ks[row][cc]) = kv.v;
#pragma unroll
            for (int j = 0; j < 8; j++) Vt[cc + j][row] = vv.s[j];
        }
        __syncthreads();

        // S = Q * K^T  (16 rows x 64 keys per wave), scaled
        f32x4 s[4];
#pragma unroll
        for (int t = 0; t < 4; t++) {
            bf16x8 b0 = *(const bf16x8*)(&Ks[t * 16 + l16][quad * 8]);
            bf16x8 b1 = *(const bf16x8*)(&Ks[t * 16 + l16][32 + quad * 8]);
            f32x4 a = {};
            a = __builtin_amdgcn_mfma_f32_16x16x32_bf16(qf[0], b0, a, 0, 0, 0);
            a = __builtin_amdgcn_mfma_f32_16x16x32_bf16(qf[1], b1, a, 0, 0, 0);
            const int keyg = key0 + t * 16 + l16;
            if (keyg < N_) {
#pragma unroll
                for (int r = 0; r < 4; r++) s[t][r] = a[r] * 0.125f;
            } else {
#pragma unroll
                for (int r = 0; r < 4; r++) s[t][r] = NEG;
            }
        }

        // online softmax per row (row = quad*4+r, cols across 16 lanes x 4 tiles)
#pragma unroll
        for (int r = 0; r < 4; r++) {
            float mx = fmaxf(fmaxf(s[0][r], s[1][r]), fmaxf(s[2][r], s[3][r]));
#pragma unroll
            for (int off = 1; off < 16; off <<= 1) mx = fmaxf(mx, __shfl_xor(mx, off));
            const float mnew = fmaxf(m_r[r], mx);
            const float alpha = __expf(fminf(m_r[r] - mnew, 0.f));
            m_r[r] = mnew;
            float rs = 0.f;
#pragma unroll
            for (int t = 0; t < 4; t++) {
                const float p = __expf(fminf(s[t][r] - mnew, 0.f));
                s[t][r] = p;
                rs += p;
            }
#pragma unroll
            for (int off = 1; off < 16; off <<= 1) rs += __shfl_xor(rs, off);
            l_r[r] = l_r[r] * alpha + rs;
#pragma unroll
            for (int t = 0; t < 4; t++) o[t][r] *= alpha;
        }

        // write P (C-layout) to LDS, reread in A-layout
#pragma unroll
        for (int t = 0; t < 4; t++)
#pragma unroll
            for (int r = 0; r < 4; r++)
                Ps[wave][quad * 4 + r][t * 16 + l16] = f2bf(s[t][r]);
        __syncthreads();

        bf16x8 pa0 = *(const bf16x8*)(&Ps[wave][l16][quad * 8]);
        bf16x8 pa1 = *(const bf16x8*)(&Ps[wave][l16][32 + quad * 8]);
#pragma unroll
        for (int t = 0; t < 4; t++) {
            bf16x8 bv0 = *(const bf16x8*)(&Vt[t * 16 + l16][quad * 8]);
            bf16x8 bv1 = *(const bf16x8*)(&Vt[t * 16 + l16][32 + quad * 8]);
            o[t] = __builtin_amdgcn_mfma_f32_16x16x32_bf16(pa0, bv0, o[t], 0, 0, 0);
            o[t] = __builtin_amdgcn_mfma_f32_16x16x32_bf16(pa1, bv1, o[t], 0, 0, 0);
        }
    }

    // epilogue: O / l -> [B,N,C] bf16
#pragma unroll
    for (int r = 0; r < 4; r++) {
        const int row = qr0 + quad * 4 + r;
        if (row < N_) {
            const float inv_l = 1.0f / l_r[r];
#pragma unroll
            for (int t = 0; t < 4; t++) {
                const int d = t * 16 + l16;
                outp[(size_t)(b * N_ + row) * C_ + h * HD + d] = f2bf(o[t][r] * inv_l);
            }
        }
    }
}

// ---------------------------------------------------------------------------
// GEMM 2: OUT(f32) = Xcat[M,1024](bf16) * Wproj[1024,1024](f32)^T + bias(f32)
// ---------------------------------------------------------------------------
__global__ __launch_bounds__(256)
void gemm_proj(const ushort_t* __restrict__ A, const float* __restrict__ Bm,
               const float* __restrict__ bias, float* __restrict__ out) {
    __shared__ ushort_t As[64][40];
    __shared__ ushort_t Bs[64][40];
    const int tid = threadIdx.x;
    const int wave = tid >> 6, lane = tid & 63;
    const int quad = lane >> 4, l16 = lane & 15;
    const int m0 = blockIdx.y * 64, n0 = blockIdx.x * 64;
    const int wm = (wave & 1) * 32, wn = (wave >> 1) * 32;
    const int lrow = tid >> 2;
    const int lcol = (tid & 3) * 8;

    f32x4 acc[2][2] = {};

    for (int k0 = 0; k0 < K_; k0 += 32) {
        uint4 av = make_uint4(0, 0, 0, 0);
        const int arow = m0 + lrow;
        if (arow < M_PROJ) av = *(const uint4*)(A + (size_t)arow * K_ + k0 + lcol);
        const float* bp = Bm + (size_t)(n0 + lrow) * K_ + k0 + lcol;
        float4 b0 = *(const float4*)bp, b1 = *(const float4*)(bp + 4);
        __syncthreads();
        *(uint4*)(&As[lrow][lcol]) = av;
        *(uint4*)(&Bs[lrow][lcol]) = packbf8(b0, b1);
        __syncthreads();
        bf16x8 af[2], bfr[2];
#pragma unroll
        for (int i = 0; i < 2; i++) {
            af[i]  = *(const bf16x8*)(&As[wm + i * 16 + l16][quad * 8]);
            bfr[i] = *(const bf16x8*)(&Bs[wn + i * 16 + l16][quad * 8]);
        }
#pragma unroll
        for (int im = 0; im < 2; im++)
#pragma unroll
            for (int in = 0; in < 2; in++)
                acc[im][in] = __builtin_amdgcn_mfma_f32_16x16x32_bf16(af[im], bfr[in], acc[im][in], 0, 0, 0);
    }

#pragma unroll
    for (int im = 0; im < 2; im++) {
#pragma unroll
        for (int in = 0; in < 2; in++) {
            const int gcol = n0 + wn + in * 16 + l16;   // 0..1023
            const float bb = bias[gcol];
#pragma unroll
            for (int r = 0; r < 4; r++) {
                const int grow = m0 + wm + im * 16 + quad * 4 + r;
                if (grow < M_PROJ)
                    out[(size_t)grow * C_ + gcol] = acc[im][in][r] + bb;
            }
        }
    }
}

// ---------------------------------------------------------------------------
// f32 in / f32 out (reference dtypes). Internals bf16.
// ws: v, xvv, xori (bf16) = 3*S1*2B = 50.4 MB. q,k (bf16) scratch in d_out
// (f32 buffer, 67.2 MB; fully overwritten by gemm_proj after q,k are dead).
// ---------------------------------------------------------------------------
extern "C" void kernel_launch(void* const* d_in, const int* in_sizes, int n_in,
                              void* d_out, int out_size, void* d_ws, size_t ws_size,
                              hipStream_t stream) {
    const float* x      = (const float*)d_in[0];
    const float* w_qkv  = (const float*)d_in[1];
    const float* w_proj = (const float*)d_in[2];
    const float* b_proj = (const float*)d_in[3];
    float* out = (float*)d_out;

    ushort_t* ws = (ushort_t*)d_ws;
    ushort_t* q    = (ushort_t*)d_out;   // scratch in d_out
    ushort_t* k    = (ushort_t*)d_out + S1;
    ushort_t* v    = ws;
    ushort_t* xvv  = ws + S1;            // [x_new (vv) ; x_ori] contiguous
    ushort_t* xori = ws + 2 * S1;

    // 1) QKV projection
    {
        dim3 grid(3072 / 64, (M_QKV + 63) / 64);   // 48 x 129
        gemm_qkv<<<grid, 256, 0, stream>>>(x, w_qkv, q, k, v);
    }
    // 2) dual attention (path 0: ori, path 1: vv)
    {
        dim3 grid((N_ + 63) / 64, B_ * H_, 2);     // 17 x 128 x 2
        attn_kernel<<<grid, 256, 0, stream>>>(q, k, v, xvv, xori);
    }
    // 3) output projection over concatenated [x_new; x_ori]
    {
        dim3 grid(1024 / 64, (M_PROJ + 63) / 64);  // 16 x 257
        gemm_proj<<<grid, 256, 0, stream>>>(xvv, w_proj, b_proj, out);
    }
}

// Round 4
// 630.186 us; speedup vs baseline: 1.0920x; 1.0920x over previous
//
#include <hip/hip_runtime.h>

typedef unsigned short ushort_t;
typedef __attribute__((ext_vector_type(8))) __bf16 bf16x8;
typedef __attribute__((ext_vector_type(4))) float f32x4;

constexpr int B_ = 8, N_ = 1025, C_ = 1024, H_ = 16, HD = 64;
constexpr int M_QKV = B_ * N_;          // 8200
constexpr int M_PROJ = 2 * B_ * N_;     // 16400
constexpr int K_ = 1024;
constexpr int NT = 1032;                // vT row stride (16B-aligned)
constexpr size_t S1 = (size_t)B_ * H_ * N_ * HD;   // 8,396,800

__device__ __forceinline__ ushort_t f2bf(float f) {
    union { float f; unsigned u; } a; a.f = f;
    unsigned r = a.u + 0x7FFFu + ((a.u >> 16) & 1u);
    return (ushort_t)(r >> 16);
}

union U4 { uint4 v; ushort_t s[8]; };

__device__ __forceinline__ uint4 packbf8(float4 a, float4 b) {
    U4 u;
    u.s[0] = f2bf(a.x); u.s[1] = f2bf(a.y); u.s[2] = f2bf(a.z); u.s[3] = f2bf(a.w);
    u.s[4] = f2bf(b.x); u.s[5] = f2bf(b.y); u.s[6] = f2bf(b.z); u.s[7] = f2bf(b.w);
    return u.v;
}

// ---------------------------------------------------------------------------
// GEMM 1: QKV = X[M,K](f32) * Wqkv[3072,K](f32)^T
//   -> q,k [B,H,N,64] bf16 ; v [B,H,N,64] bf16 ; vT [B,H,64,NT] bf16
// ---------------------------------------------------------------------------
__global__ __launch_bounds__(256)
void gemm_qkv(const float* __restrict__ A, const float* __restrict__ Bm,
              ushort_t* __restrict__ q, ushort_t* __restrict__ k,
              ushort_t* __restrict__ v, ushort_t* __restrict__ vT) {
    __shared__ ushort_t As[64][40];
    __shared__ ushort_t Bs[64][40];
    const int tid = threadIdx.x;
    const int wave = tid >> 6, lane = tid & 63;
    const int quad = lane >> 4, l16 = lane & 15;
    const int m0 = blockIdx.y * 64, n0 = blockIdx.x * 64;
    const int wm = (wave & 1) * 32, wn = (wave >> 1) * 32;
    const int lrow = tid >> 2;           // 0..63
    const int lcol = (tid & 3) * 8;      // 0,8,16,24

    f32x4 acc[2][2] = {};

    for (int k0 = 0; k0 < K_; k0 += 32) {
        float4 a0 = make_float4(0, 0, 0, 0), a1 = a0, b0, b1;
        const int arow = m0 + lrow;
        if (arow < M_QKV) {
            const float* ap = A + (size_t)arow * K_ + k0 + lcol;
            a0 = *(const float4*)ap; a1 = *(const float4*)(ap + 4);
        }
        const float* bp = Bm + (size_t)(n0 + lrow) * K_ + k0 + lcol;
        b0 = *(const float4*)bp; b1 = *(const float4*)(bp + 4);
        __syncthreads();
        *(uint4*)(&As[lrow][lcol]) = packbf8(a0, a1);
        *(uint4*)(&Bs[lrow][lcol]) = packbf8(b0, b1);
        __syncthreads();
        bf16x8 af[2], bfr[2];
#pragma unroll
        for (int i = 0; i < 2; i++) {
            af[i]  = *(const bf16x8*)(&As[wm + i * 16 + l16][quad * 8]);
            bfr[i] = *(const bf16x8*)(&Bs[wn + i * 16 + l16][quad * 8]);
        }
#pragma unroll
        for (int im = 0; im < 2; im++)
#pragma unroll
            for (int in = 0; in < 2; in++)
                acc[im][in] = __builtin_amdgcn_mfma_f32_16x16x32_bf16(af[im], bfr[in], acc[im][in], 0, 0, 0);
    }

#pragma unroll
    for (int im = 0; im < 2; im++) {
#pragma unroll
        for (int in = 0; in < 2; in++) {
            const int gcol = n0 + wn + in * 16 + l16;     // 0..3071
            const int which = gcol >> 10;                 // 0/1/2
            const int c = gcol & 1023;
            const int h = c >> 6, d = c & 63;
            ushort_t* dst = which == 0 ? q : (which == 1 ? k : v);
#pragma unroll
            for (int r = 0; r < 4; r++) {
                const int grow = m0 + wm + im * 16 + quad * 4 + r;
                if (grow < M_QKV) {
                    const int b = grow / N_;
                    const int nn = grow - b * N_;
                    const ushort_t val = f2bf(acc[im][in][r]);
                    const size_t bh = (size_t)(b * H_ + h);
                    dst[(bh * N_ + nn) * HD + d] = val;
                    if (which == 2)
                        vT[(bh * HD + d) * NT + nn] = val;   // transposed copy
                }
            }
        }
    }
}

// ---------------------------------------------------------------------------
// Attention (both paths fused per block). Block = (qtile, bh).
//   path0: S=q·k^T -> x_ori ; path1: S=v·v^T -> x_new
// ---------------------------------------------------------------------------
__device__ __forceinline__ void softmax_update(f32x4 (&s)[4], float (&m_)[4],
                                               float (&l_)[4], f32x4 (&o)[4]) {
#pragma unroll
    for (int r = 0; r < 4; r++) {
        float mx = fmaxf(fmaxf(s[0][r], s[1][r]), fmaxf(s[2][r], s[3][r]));
#pragma unroll
        for (int off = 1; off < 16; off <<= 1) mx = fmaxf(mx, __shfl_xor(mx, off));
        const float mnew = fmaxf(m_[r], mx);
        const float alpha = __expf(fminf(m_[r] - mnew, 0.f));
        m_[r] = mnew;
        float rs = 0.f;
#pragma unroll
        for (int t = 0; t < 4; t++) {
            const float p = __expf(fminf(s[t][r] - mnew, 0.f));
            s[t][r] = p;
            rs += p;
        }
#pragma unroll
        for (int off = 1; off < 16; off <<= 1) rs += __shfl_xor(rs, off);
        l_[r] = l_[r] * alpha + rs;
#pragma unroll
        for (int t = 0; t < 4; t++) o[t][r] *= alpha;
    }
}

__global__ __launch_bounds__(256, 4)
void attn_kernel(const ushort_t* __restrict__ q, const ushort_t* __restrict__ k,
                 const ushort_t* __restrict__ v, const ushort_t* __restrict__ vT,
                 ushort_t* __restrict__ xvv, ushort_t* __restrict__ xori) {
    __shared__ ushort_t Ks[64][72];    // k tile   [key][dim]
    __shared__ ushort_t Vs[64][72];    // v tile   [key][dim]  (path1 K-operand)
    __shared__ ushort_t Vt[64][72];    // v^T tile [dim][key]  (PV B-operand)
    __shared__ ushort_t Ps[4][16][72]; // per-wave P buffer (wave-private, reused per path)

    const int tid = threadIdx.x;
    const int wave = tid >> 6, lane = tid & 63;
    const int quad = lane >> 4, l16 = lane & 15;
    const int bh = blockIdx.y;
    const int b = bh >> 4, h = bh & 15;

    const size_t base  = (size_t)bh * N_ * HD;
    const size_t baseT = (size_t)bh * HD * NT;
    const int qr0 = blockIdx.x * 64 + wave * 16;
    const float NEG = -30000.0f;

    // Q fragments for both paths (16 rows x 64 dims per wave)
    bf16x8 qq[2], qv[2];
    {
        const int qrow = qr0 + l16;
#pragma unroll
        for (int kk = 0; kk < 2; kk++) {
            U4 uq, uv; uq.v = make_uint4(0, 0, 0, 0); uv.v = uq.v;
            if (qrow < N_) {
                uq.v = *(const uint4*)(q + base + (size_t)qrow * HD + kk * 32 + quad * 8);
                uv.v = *(const uint4*)(v + base + (size_t)qrow * HD + kk * 32 + quad * 8);
            }
            qq[kk] = *(const bf16x8*)uq.s;
            qv[kk] = *(const bf16x8*)uv.s;
        }
    }

    float m0_[4], l0_[4], m1_[4], l1_[4];
    f32x4 o0[4] = {}, o1[4] = {};
#pragma unroll
    for (int r = 0; r < 4; r++) { m0_[r] = NEG; l0_[r] = 0.f; m1_[r] = NEG; l1_[r] = 0.f; }

    const int nkt = (N_ + 63) / 64;  // 17
    for (int kt = 0; kt < nkt; kt++) {
        const int key0 = kt * 64;
        __syncthreads();
        // stage k-tile, v-tile (row-major) + vT-tile (all vectorized b128)
#pragma unroll
        for (int i = 0; i < 2; i++) {
            const int c = tid + i * 256;       // 0..511
            const int row = c >> 3;            // key (or dim for Vt) within tile
            const int cc = (c & 7) * 8;        // dim (or key for Vt) start
            const int key = key0 + row;
            uint4 kv = make_uint4(0, 0, 0, 0), vv = kv;
            if (key < N_) {
                kv = *(const uint4*)(k + base + (size_t)key * HD + cc);
                vv = *(const uint4*)(v + base + (size_t)key * HD + cc);
            }
            // vT: row=dim (always valid), cc=key offset; OOB keys masked via s=NEG
            uint4 tv = *(const uint4*)(vT + baseT + (size_t)row * NT + key0 + cc);
            *(uint4*)(&Ks[row][cc]) = kv;
            *(uint4*)(&Vs[row][cc]) = vv;
            *(uint4*)(&Vt[row][cc]) = tv;
        }
        __syncthreads();

#pragma unroll
        for (int path = 0; path < 2; path++) {
            // S = Q * K^T (16 rows x 64 keys per wave), scaled by 1/8
            f32x4 s[4];
#pragma unroll
            for (int t = 0; t < 4; t++) {
                const ushort_t (&Kt)[64][72] = (path == 0) ? Ks : Vs;
                bf16x8 b0 = *(const bf16x8*)(&Kt[t * 16 + l16][quad * 8]);
                bf16x8 b1 = *(const bf16x8*)(&Kt[t * 16 + l16][32 + quad * 8]);
                f32x4 a = {};
                a = __builtin_amdgcn_mfma_f32_16x16x32_bf16(path == 0 ? qq[0] : qv[0], b0, a, 0, 0, 0);
                a = __builtin_amdgcn_mfma_f32_16x16x32_bf16(path == 0 ? qq[1] : qv[1], b1, a, 0, 0, 0);
                const int keyg = key0 + t * 16 + l16;
                if (keyg < N_) {
#pragma unroll
                    for (int r = 0; r < 4; r++) s[t][r] = a[r] * 0.125f;
                } else {
#pragma unroll
                    for (int r = 0; r < 4; r++) s[t][r] = NEG;
                }
            }

            if (path == 0) softmax_update(s, m0_, l0_, o0);
            else           softmax_update(s, m1_, l1_, o1);

            // P: C-layout -> LDS -> A-layout (wave-private buffer, no barrier)
#pragma unroll
            for (int t = 0; t < 4; t++)
#pragma unroll
                for (int r = 0; r < 4; r++)
                    Ps[wave][quad * 4 + r][t * 16 + l16] = f2bf(s[t][r]);

            bf16x8 pa0 = *(const bf16x8*)(&Ps[wave][l16][quad * 8]);
            bf16x8 pa1 = *(const bf16x8*)(&Ps[wave][l16][32 + quad * 8]);
#pragma unroll
            for (int t = 0; t < 4; t++) {
                bf16x8 bv0 = *(const bf16x8*)(&Vt[t * 16 + l16][quad * 8]);
                bf16x8 bv1 = *(const bf16x8*)(&Vt[t * 16 + l16][32 + quad * 8]);
                if (path == 0) {
                    o0[t] = __builtin_amdgcn_mfma_f32_16x16x32_bf16(pa0, bv0, o0[t], 0, 0, 0);
                    o0[t] = __builtin_amdgcn_mfma_f32_16x16x32_bf16(pa1, bv1, o0[t], 0, 0, 0);
                } else {
                    o1[t] = __builtin_amdgcn_mfma_f32_16x16x32_bf16(pa0, bv0, o1[t], 0, 0, 0);
                    o1[t] = __builtin_amdgcn_mfma_f32_16x16x32_bf16(pa1, bv1, o1[t], 0, 0, 0);
                }
            }
        }
    }

    // epilogue: O / l -> [B,N,C] bf16 for both paths
#pragma unroll
    for (int r = 0; r < 4; r++) {
        const int row = qr0 + quad * 4 + r;
        if (row < N_) {
            const float inv0 = 1.0f / l0_[r];
            const float inv1 = 1.0f / l1_[r];
            const size_t rb = (size_t)(b * N_ + row) * C_ + h * HD;
#pragma unroll
            for (int t = 0; t < 4; t++) {
                const int d = t * 16 + l16;
                xori[rb + d] = f2bf(o0[t][r] * inv0);
                xvv[rb + d]  = f2bf(o1[t][r] * inv1);
            }
        }
    }
}

// ---------------------------------------------------------------------------
// GEMM 2: OUT(f32) = Xcat[M,1024](bf16) * Wproj[1024,1024](f32)^T + bias(f32)
// ---------------------------------------------------------------------------
__global__ __launch_bounds__(256)
void gemm_proj(const ushort_t* __restrict__ A, const float* __restrict__ Bm,
               const float* __restrict__ bias, float* __restrict__ out) {
    __shared__ ushort_t As[64][40];
    __shared__ ushort_t Bs[64][40];
    const int tid = threadIdx.x;
    const int wave = tid >> 6, lane = tid & 63;
    const int quad = lane >> 4, l16 = lane & 15;
    const int m0 = blockIdx.y * 64, n0 = blockIdx.x * 64;
    const int wm = (wave & 1) * 32, wn = (wave >> 1) * 32;
    const int lrow = tid >> 2;
    const int lcol = (tid & 3) * 8;

    f32x4 acc[2][2] = {};

    for (int k0 = 0; k0 < K_; k0 += 32) {
        uint4 av = make_uint4(0, 0, 0, 0);
        const int arow = m0 + lrow;
        if (arow < M_PROJ) av = *(const uint4*)(A + (size_t)arow * K_ + k0 + lcol);
        const float* bp = Bm + (size_t)(n0 + lrow) * K_ + k0 + lcol;
        float4 b0 = *(const float4*)bp, b1 = *(const float4*)(bp + 4);
        __syncthreads();
        *(uint4*)(&As[lrow][lcol]) = av;
        *(uint4*)(&Bs[lrow][lcol]) = packbf8(b0, b1);
        __syncthreads();
        bf16x8 af[2], bfr[2];
#pragma unroll
        for (int i = 0; i < 2; i++) {
            af[i]  = *(const bf16x8*)(&As[wm + i * 16 + l16][quad * 8]);
            bfr[i] = *(const bf16x8*)(&Bs[wn + i * 16 + l16][quad * 8]);
        }
#pragma unroll
        for (int im = 0; im < 2; im++)
#pragma unroll
            for (int in = 0; in < 2; in++)
                acc[im][in] = __builtin_amdgcn_mfma_f32_16x16x32_bf16(af[im], bfr[in], acc[im][in], 0, 0, 0);
    }

#pragma unroll
    for (int im = 0; im < 2; im++) {
#pragma unroll
        for (int in = 0; in < 2; in++) {
            const int gcol = n0 + wn + in * 16 + l16;   // 0..1023
            const float bb = bias[gcol];
#pragma unroll
            for (int r = 0; r < 4; r++) {
                const int grow = m0 + wm + im * 16 + quad * 4 + r;
                if (grow < M_PROJ)
                    out[(size_t)grow * C_ + gcol] = acc[im][in][r] + bb;
            }
        }
    }
}

// ---------------------------------------------------------------------------
// f32 in / f32 out. Internals bf16.
// Scratch map: d_out (33.59M ushort capacity) holds q[S1], k[S1], vT[8.45M]
//   (all dead before gemm_proj overwrites d_out). d_ws holds v, xvv, xori (3*S1).
// ---------------------------------------------------------------------------
extern "C" void kernel_launch(void* const* d_in, const int* in_sizes, int n_in,
                              void* d_out, int out_size, void* d_ws, size_t ws_size,
                              hipStream_t stream) {
    const float* x      = (const float*)d_in[0];
    const float* w_qkv  = (const float*)d_in[1];
    const float* w_proj = (const float*)d_in[2];
    const float* b_proj = (const float*)d_in[3];
    float* out = (float*)d_out;

    ushort_t* ws = (ushort_t*)d_ws;
    ushort_t* q    = (ushort_t*)d_out;
    ushort_t* k    = (ushort_t*)d_out + S1;
    ushort_t* vT   = (ushort_t*)d_out + 2 * S1;   // [B*H][64][NT]
    ushort_t* v    = ws;
    ushort_t* xvv  = ws + S1;                      // [x_new ; x_ori] contiguous
    ushort_t* xori = ws + 2 * S1;

    // 1) QKV projection (+ vT transposed copy of v)
    {
        dim3 grid(3072 / 64, (M_QKV + 63) / 64);   // 48 x 129
        gemm_qkv<<<grid, 256, 0, stream>>>(x, w_qkv, q, k, v, vT);
    }
    // 2) dual attention, both paths fused per block
    {
        dim3 grid((N_ + 63) / 64, B_ * H_);        // 17 x 128
        attn_kernel<<<grid, 256, 0, stream>>>(q, k, v, vT, xvv, xori);
    }
    // 3) output projection over concatenated [x_new; x_ori]
    {
        dim3 grid(1024 / 64, (M_PROJ + 63) / 64);  // 16 x 257
        gemm_proj<<<grid, 256, 0, stream>>>(xvv, w_proj, b_proj, out);
    }
}

// Round 5
// 583.696 us; speedup vs baseline: 1.1790x; 1.0796x over previous
//
#include <hip/hip_runtime.h>

typedef unsigned short ushort_t;
typedef __attribute__((ext_vector_type(8))) __bf16 bf16x8;
typedef __attribute__((ext_vector_type(4))) float f32x4;

constexpr int B_ = 8, N_ = 1025, C_ = 1024, H_ = 16, HD = 64;
constexpr int M_QKV = B_ * N_;          // 8200
constexpr int M_PROJ = 2 * B_ * N_;     // 16400
constexpr int K_ = 1024;
constexpr int NT = 1032;                // vT row stride (16B-aligned)
constexpr size_t S1 = (size_t)B_ * H_ * N_ * HD;   // 8,396,800

// exact RNE (used only in low-volume epilogues)
__device__ __forceinline__ ushort_t f2bf(float f) {
    union { float f; unsigned u; } a; a.f = f;
    unsigned r = a.u + 0x7FFFu + ((a.u >> 16) & 1u);
    return (ushort_t)(r >> 16);
}
// fast round-half-up bf16 (2 insts/value) for hot paths
__device__ __forceinline__ ushort_t f2bf_fast(float f) {
    return (ushort_t)((__float_as_uint(f) + 0x8000u) >> 16);
}
__device__ __forceinline__ unsigned pk2(float x, float y) {
    unsigned a = __float_as_uint(x) + 0x8000u;
    unsigned b = __float_as_uint(y) + 0x8000u;
    return (a >> 16) | (b & 0xffff0000u);
}
__device__ __forceinline__ uint4 pack8(float4 x, float4 y) {
    return make_uint4(pk2(x.x, x.y), pk2(x.z, x.w), pk2(y.x, y.y), pk2(y.z, y.w));
}

union U4 { uint4 v; ushort_t s[8]; };

// ---------------------------------------------------------------------------
// GEMM 1: QKV = X[M,K](f32) * Wqkv[3072,K](f32)^T  (128x128x32 tiles)
//   -> q,k,v [B,H,N,64] bf16 ; vT [B,H,64,NT] bf16
// ---------------------------------------------------------------------------
__global__ __launch_bounds__(256)
void gemm_qkv(const float* __restrict__ A, const float* __restrict__ Bm,
              ushort_t* __restrict__ q, ushort_t* __restrict__ k,
              ushort_t* __restrict__ v, ushort_t* __restrict__ vT) {
    __shared__ ushort_t As[128][40];
    __shared__ ushort_t Bs[128][40];
    const int tid = threadIdx.x;
    const int wave = tid >> 6, lane = tid & 63;
    const int quad = lane >> 4, l16 = lane & 15;
    const int m0 = blockIdx.y * 128, n0 = blockIdx.x * 128;
    const int wm = (wave & 1) * 64, wn = (wave >> 1) * 64;
    const int lrow = tid >> 1;           // 0..127
    const int lcol = (tid & 1) * 16;     // 0 or 16

    f32x4 acc[4][4] = {};

    for (int k0 = 0; k0 < K_; k0 += 32) {
        float4 a4[4], b4[4];
        const int arow = m0 + lrow;
        const bool aok = arow < M_QKV;
        const float* ap = A + (size_t)arow * K_ + k0 + lcol;
        const float* bp = Bm + (size_t)(n0 + lrow) * K_ + k0 + lcol;
#pragma unroll
        for (int i = 0; i < 4; i++) {
            a4[i] = aok ? *(const float4*)(ap + i * 4) : make_float4(0, 0, 0, 0);
            b4[i] = *(const float4*)(bp + i * 4);
        }
        __syncthreads();
        *(uint4*)(&As[lrow][lcol])     = pack8(a4[0], a4[1]);
        *(uint4*)(&As[lrow][lcol + 8]) = pack8(a4[2], a4[3]);
        *(uint4*)(&Bs[lrow][lcol])     = pack8(b4[0], b4[1]);
        *(uint4*)(&Bs[lrow][lcol + 8]) = pack8(b4[2], b4[3]);
        __syncthreads();
        bf16x8 af[4], bfr[4];
#pragma unroll
        for (int i = 0; i < 4; i++) {
            af[i]  = *(const bf16x8*)(&As[wm + i * 16 + l16][quad * 8]);
            bfr[i] = *(const bf16x8*)(&Bs[wn + i * 16 + l16][quad * 8]);
        }
#pragma unroll
        for (int im = 0; im < 4; im++)
#pragma unroll
            for (int in = 0; in < 4; in++)
                acc[im][in] = __builtin_amdgcn_mfma_f32_16x16x32_bf16(af[im], bfr[in], acc[im][in], 0, 0, 0);
    }

#pragma unroll
    for (int im = 0; im < 4; im++) {
#pragma unroll
        for (int in = 0; in < 4; in++) {
            const int gcol = n0 + wn + in * 16 + l16;     // 0..3071
            const int which = gcol >> 10;                 // 0/1/2
            const int c = gcol & 1023;
            const int h = c >> 6, d = c & 63;
            ushort_t* dst = which == 0 ? q : (which == 1 ? k : v);
#pragma unroll
            for (int r = 0; r < 4; r++) {
                const int grow = m0 + wm + im * 16 + quad * 4 + r;
                if (grow < M_QKV) {
                    const int b = grow / N_;
                    const int nn = grow - b * N_;
                    const ushort_t val = f2bf(acc[im][in][r]);
                    const size_t bh = (size_t)(b * H_ + h);
                    dst[(bh * N_ + nn) * HD + d] = val;
                    if (which == 2)
                        vT[(bh * HD + d) * NT + nn] = val;   // transposed copy
                }
            }
        }
    }
}

// ---------------------------------------------------------------------------
// Attention (both paths fused). Block = (qtile, bh).
//   path0: S=q·k^T -> x_ori ; path1: S=v·v^T -> x_new
// Un-normalized exponentials (scores bounded, no overflow); l reduced once at end.
// ---------------------------------------------------------------------------
__global__ __launch_bounds__(256, 4)
void attn_kernel(const ushort_t* __restrict__ q, const ushort_t* __restrict__ k,
                 const ushort_t* __restrict__ v, const ushort_t* __restrict__ vT,
                 ushort_t* __restrict__ xvv, ushort_t* __restrict__ xori) {
    __shared__ ushort_t Ks[64][72];    // k tile   [key][dim]
    __shared__ ushort_t Vs[64][72];    // v tile   [key][dim]  (path1 K-operand)
    __shared__ ushort_t Vt[64][72];    // v^T tile [dim][key]  (PV B-operand)
    __shared__ ushort_t Ps[4][16][72]; // per-wave P buffer (wave-private)

    const int tid = threadIdx.x;
    const int wave = tid >> 6, lane = tid & 63;
    const int quad = lane >> 4, l16 = lane & 15;
    const int bh = blockIdx.y;
    const int b = bh >> 4, h = bh & 15;

    const size_t base  = (size_t)bh * N_ * HD;
    const size_t baseT = (size_t)bh * HD * NT;
    const int qr0 = blockIdx.x * 64 + wave * 16;

    // Q fragments for both paths (16 rows x 64 dims per wave)
    bf16x8 qq[2], qv[2];
    {
        const int qrow = qr0 + l16;
#pragma unroll
        for (int kk = 0; kk < 2; kk++) {
            U4 uq, uv; uq.v = make_uint4(0, 0, 0, 0); uv.v = uq.v;
            if (qrow < N_) {
                uq.v = *(const uint4*)(q + base + (size_t)qrow * HD + kk * 32 + quad * 8);
                uv.v = *(const uint4*)(v + base + (size_t)qrow * HD + kk * 32 + quad * 8);
            }
            qq[kk] = *(const bf16x8*)uq.s;
            qv[kk] = *(const bf16x8*)uv.s;
        }
    }

    float l0a[4] = {0.f, 0.f, 0.f, 0.f}, l1a[4] = {0.f, 0.f, 0.f, 0.f};
    f32x4 o0[4] = {}, o1[4] = {};

    const int nkt = (N_ + 63) / 64;  // 17
    for (int kt = 0; kt < nkt; kt++) {
        const int key0 = kt * 64;
        __syncthreads();
        // stage k-tile, v-tile, vT-tile (all vectorized b128)
#pragma unroll
        for (int i = 0; i < 2; i++) {
            const int c = tid + i * 256;       // 0..511
            const int row = c >> 3;
            const int cc = (c & 7) * 8;
            const int key = key0 + row;
            uint4 kv = make_uint4(0, 0, 0, 0), vv = kv;
            if (key < N_) {
                kv = *(const uint4*)(k + base + (size_t)key * HD + cc);
                vv = *(const uint4*)(v + base + (size_t)key * HD + cc);
            }
            uint4 tv = *(const uint4*)(vT + baseT + (size_t)row * NT + key0 + cc);
            *(uint4*)(&Ks[row][cc]) = kv;
            *(uint4*)(&Vs[row][cc]) = vv;
            *(uint4*)(&Vt[row][cc]) = tv;
        }
        __syncthreads();

#pragma unroll
        for (int path = 0; path < 2; path++) {
            // S = Q * K^T (16 rows x 64 keys per wave); p = exp(s/8) un-normalized
            f32x4 s[4];
#pragma unroll
            for (int t = 0; t < 4; t++) {
                const ushort_t (&Kt)[64][72] = (path == 0) ? Ks : Vs;
                bf16x8 b0 = *(const bf16x8*)(&Kt[t * 16 + l16][quad * 8]);
                bf16x8 b1 = *(const bf16x8*)(&Kt[t * 16 + l16][32 + quad * 8]);
                f32x4 a = {};
                a = __builtin_amdgcn_mfma_f32_16x16x32_bf16(path == 0 ? qq[0] : qv[0], b0, a, 0, 0, 0);
                a = __builtin_amdgcn_mfma_f32_16x16x32_bf16(path == 0 ? qq[1] : qv[1], b1, a, 0, 0, 0);
                const int keyg = key0 + t * 16 + l16;
                if (keyg < N_) {
#pragma unroll
                    for (int r = 0; r < 4; r++) s[t][r] = __expf(a[r] * 0.125f);
                } else {
#pragma unroll
                    for (int r = 0; r < 4; r++) s[t][r] = 0.f;
                }
            }

            // per-lane partial row sums (reduced once at the end)
            float* la = (path == 0) ? l0a : l1a;
#pragma unroll
            for (int r = 0; r < 4; r++)
                la[r] += (s[0][r] + s[1][r]) + (s[2][r] + s[3][r]);

            // P: C-layout -> LDS -> A-layout (wave-private, no barrier)
#pragma unroll
            for (int t = 0; t < 4; t++)
#pragma unroll
                for (int r = 0; r < 4; r++)
                    Ps[wave][quad * 4 + r][t * 16 + l16] = f2bf_fast(s[t][r]);

            bf16x8 pa0 = *(const bf16x8*)(&Ps[wave][l16][quad * 8]);
            bf16x8 pa1 = *(const bf16x8*)(&Ps[wave][l16][32 + quad * 8]);
#pragma unroll
            for (int t = 0; t < 4; t++) {
                bf16x8 bv0 = *(const bf16x8*)(&Vt[t * 16 + l16][quad * 8]);
                bf16x8 bv1 = *(const bf16x8*)(&Vt[t * 16 + l16][32 + quad * 8]);
                if (path == 0) {
                    o0[t] = __builtin_amdgcn_mfma_f32_16x16x32_bf16(pa0, bv0, o0[t], 0, 0, 0);
                    o0[t] = __builtin_amdgcn_mfma_f32_16x16x32_bf16(pa1, bv1, o0[t], 0, 0, 0);
                } else {
                    o1[t] = __builtin_amdgcn_mfma_f32_16x16x32_bf16(pa0, bv0, o1[t], 0, 0, 0);
                    o1[t] = __builtin_amdgcn_mfma_f32_16x16x32_bf16(pa1, bv1, o1[t], 0, 0, 0);
                }
            }
        }
    }

    // final row-sum reduction (16 lanes within quad) + normalize + store
#pragma unroll
    for (int r = 0; r < 4; r++) {
        float L0 = l0a[r], L1 = l1a[r];
#pragma unroll
        for (int off = 1; off < 16; off <<= 1) {
            L0 += __shfl_xor(L0, off);
            L1 += __shfl_xor(L1, off);
        }
        const int row = qr0 + quad * 4 + r;
        if (row < N_) {
            const float inv0 = 1.0f / L0;
            const float inv1 = 1.0f / L1;
            const size_t rb = (size_t)(b * N_ + row) * C_ + h * HD;
#pragma unroll
            for (int t = 0; t < 4; t++) {
                const int d = t * 16 + l16;
                xori[rb + d] = f2bf(o0[t][r] * inv0);
                xvv[rb + d]  = f2bf(o1[t][r] * inv1);
            }
        }
    }
}

// ---------------------------------------------------------------------------
// GEMM 2: OUT(f32) = Xcat[M,1024](bf16) * Wproj[1024,1024](f32)^T + bias(f32)
// 128x128x32 tiles
// ---------------------------------------------------------------------------
__global__ __launch_bounds__(256)
void gemm_proj(const ushort_t* __restrict__ A, const float* __restrict__ Bm,
               const float* __restrict__ bias, float* __restrict__ out) {
    __shared__ ushort_t As[128][40];
    __shared__ ushort_t Bs[128][40];
    const int tid = threadIdx.x;
    const int wave = tid >> 6, lane = tid & 63;
    const int quad = lane >> 4, l16 = lane & 15;
    const int m0 = blockIdx.y * 128, n0 = blockIdx.x * 128;
    const int wm = (wave & 1) * 64, wn = (wave >> 1) * 64;
    const int lrow = tid >> 1;           // 0..127
    const int lcol = (tid & 1) * 16;     // 0 or 16

    f32x4 acc[4][4] = {};

    for (int k0 = 0; k0 < K_; k0 += 32) {
        uint4 a0 = make_uint4(0, 0, 0, 0), a1 = a0;
        const int arow = m0 + lrow;
        if (arow < M_PROJ) {
            const ushort_t* ap = A + (size_t)arow * K_ + k0 + lcol;
            a0 = *(const uint4*)ap;
            a1 = *(const uint4*)(ap + 8);
        }
        float4 b4[4];
        const float* bp = Bm + (size_t)(n0 + lrow) * K_ + k0 + lcol;
#pragma unroll
        for (int i = 0; i < 4; i++) b4[i] = *(const float4*)(bp + i * 4);
        __syncthreads();
        *(uint4*)(&As[lrow][lcol])     = a0;
        *(uint4*)(&As[lrow][lcol + 8]) = a1;
        *(uint4*)(&Bs[lrow][lcol])     = pack8(b4[0], b4[1]);
        *(uint4*)(&Bs[lrow][lcol + 8]) = pack8(b4[2], b4[3]);
        __syncthreads();
        bf16x8 af[4], bfr[4];
#pragma unroll
        for (int i = 0; i < 4; i++) {
            af[i]  = *(const bf16x8*)(&As[wm + i * 16 + l16][quad * 8]);
            bfr[i] = *(const bf16x8*)(&Bs[wn + i * 16 + l16][quad * 8]);
        }
#pragma unroll
        for (int im = 0; im < 4; im++)
#pragma unroll
            for (int in = 0; in < 4; in++)
                acc[im][in] = __builtin_amdgcn_mfma_f32_16x16x32_bf16(af[im], bfr[in], acc[im][in], 0, 0, 0);
    }

#pragma unroll
    for (int im = 0; im < 4; im++) {
#pragma unroll
        for (int in = 0; in < 4; in++) {
            const int gcol = n0 + wn + in * 16 + l16;   // 0..1023
            const float bb = bias[gcol];
#pragma unroll
            for (int r = 0; r < 4; r++) {
                const int grow = m0 + wm + im * 16 + quad * 4 + r;
                if (grow < M_PROJ)
                    out[(size_t)grow * C_ + gcol] = acc[im][in][r] + bb;
            }
        }
    }
}

// ---------------------------------------------------------------------------
// f32 in / f32 out. Internals bf16.
// Scratch: d_out holds q[S1], k[S1], vT[8.45M] (dead before gemm_proj).
// d_ws holds v, xvv, xori (3*S1).
// ---------------------------------------------------------------------------
extern "C" void kernel_launch(void* const* d_in, const int* in_sizes, int n_in,
                              void* d_out, int out_size, void* d_ws, size_t ws_size,
                              hipStream_t stream) {
    const float* x      = (const float*)d_in[0];
    const float* w_qkv  = (const float*)d_in[1];
    const float* w_proj = (const float*)d_in[2];
    const float* b_proj = (const float*)d_in[3];
    float* out = (float*)d_out;

    ushort_t* ws = (ushort_t*)d_ws;
    ushort_t* q    = (ushort_t*)d_out;
    ushort_t* k    = (ushort_t*)d_out + S1;
    ushort_t* vT   = (ushort_t*)d_out + 2 * S1;   // [B*H][64][NT]
    ushort_t* v    = ws;
    ushort_t* xvv  = ws + S1;                      // [x_new ; x_ori] contiguous
    ushort_t* xori = ws + 2 * S1;

    // 1) QKV projection (+ vT transposed copy of v)
    {
        dim3 grid(3072 / 128, (M_QKV + 127) / 128);   // 24 x 65
        gemm_qkv<<<grid, 256, 0, stream>>>(x, w_qkv, q, k, v, vT);
    }
    // 2) dual attention, both paths fused per block
    {
        dim3 grid((N_ + 63) / 64, B_ * H_);           // 17 x 128
        attn_kernel<<<grid, 256, 0, stream>>>(q, k, v, vT, xvv, xori);
    }
    // 3) output projection over concatenated [x_new; x_ori]
    {
        dim3 grid(1024 / 128, (M_PROJ + 127) / 128);  // 8 x 129
        gemm_proj<<<grid, 256, 0, stream>>>(xvv, w_proj, b_proj, out);
    }
}

// Round 6
// 414.287 us; speedup vs baseline: 1.6611x; 1.4089x over previous
//
#include <hip/hip_runtime.h>

typedef unsigned short ushort_t;
typedef __attribute__((ext_vector_type(8))) __bf16 bf16x8;
typedef __attribute__((ext_vector_type(4))) float f32x4;

constexpr int B_ = 8, N_ = 1025, C_ = 1024, H_ = 16, HD = 64;
constexpr int M_QKV = B_ * N_;          // 8200
constexpr int M_PROJ = 2 * B_ * N_;     // 16400
constexpr int K_ = 1024;
constexpr int NT = 1032;                // vT row stride (16B-aligned)
constexpr size_t S1 = (size_t)B_ * H_ * N_ * HD;   // 8,396,800
constexpr size_t VT_SZ = (size_t)B_ * H_ * HD * NT; // 8,454,144

// exact RNE (low-volume epilogues)
__device__ __forceinline__ ushort_t f2bf(float f) {
    union { float f; unsigned u; } a; a.f = f;
    unsigned r = a.u + 0x7FFFu + ((a.u >> 16) & 1u);
    return (ushort_t)(r >> 16);
}
// fast round-half-up bf16 for hot paths
__device__ __forceinline__ ushort_t f2bf_fast(float f) {
    return (ushort_t)((__float_as_uint(f) + 0x8000u) >> 16);
}
__device__ __forceinline__ unsigned pk2(float x, float y) {
    unsigned a = __float_as_uint(x) + 0x8000u;
    unsigned b = __float_as_uint(y) + 0x8000u;
    return (a >> 16) | (b & 0xffff0000u);
}
__device__ __forceinline__ uint4 pack8(float4 x, float4 y) {
    return make_uint4(pk2(x.x, x.y), pk2(x.z, x.w), pk2(y.x, y.y), pk2(y.z, y.w));
}

union U4 { uint4 v; ushort_t s[8]; };

// async global->LDS, 16B per lane (dest = wave-uniform base + lane*16)
__device__ __forceinline__ void gload16(const ushort_t* g, ushort_t* l) {
    __builtin_amdgcn_global_load_lds(
        (const __attribute__((address_space(1))) void*)g,
        (__attribute__((address_space(3))) void*)l, 16, 0, 0);
}

// ---------------------------------------------------------------------------
// f32 -> bf16 pack (8 elems/thread)
// ---------------------------------------------------------------------------
__global__ __launch_bounds__(256)
void conv_bf16(const float* __restrict__ src, ushort_t* __restrict__ dst, int n8) {
    const int i = blockIdx.x * 256 + threadIdx.x;
    if (i < n8) {
        const float4* s = (const float4*)src + 2 * (size_t)i;
        ((uint4*)dst)[i] = pack8(s[0], s[1]);
    }
}

// ---------------------------------------------------------------------------
// GEMM 1 (m97-style): QKV = Xbf[M,1024] * Wbf[3072,1024]^T, 128x128x32 tiles
//   -> q,k,v [B,H,N,64] bf16 ; vT [B,H,64,NT] bf16
// ---------------------------------------------------------------------------
__global__ __launch_bounds__(256)
void gemm_qkv(const ushort_t* __restrict__ A, const ushort_t* __restrict__ Bm,
              ushort_t* __restrict__ q, ushort_t* __restrict__ k,
              ushort_t* __restrict__ v, ushort_t* __restrict__ vT) {
    __shared__ ushort_t As[128 * 32];
    __shared__ ushort_t Bs[128 * 32];
    const int tid = threadIdx.x;
    const int wave = tid >> 6, lane = tid & 63;
    const int quad = lane >> 4, l16 = lane & 15;
    const int m0 = blockIdx.y * 128, n0 = blockIdx.x * 128;
    const int wm = (wave & 1) * 64, wn = (wave >> 1) * 64;

    // staging: linear16 = tid + r*256; row=linear16>>2, col8=(linear16&3)*8
    const int col8 = (tid & 3) * 8;
    const int row0 = tid >> 2;                          // 0..63
    const int ar0 = min(m0 + row0,      M_QKV - 1);     // clamp (garbage rows never stored)
    const int ar1 = min(m0 + row0 + 64, M_QKV - 1);
    const ushort_t* ga0 = A + (size_t)ar0 * K_ + col8;
    const ushort_t* ga1 = A + (size_t)ar1 * K_ + col8;
    const ushort_t* gb0 = Bm + (size_t)(n0 + row0) * K_ + col8;
    const ushort_t* gb1 = Bm + (size_t)(n0 + row0 + 64) * K_ + col8;
    ushort_t* lA0 = As + tid * 8;
    ushort_t* lA1 = As + (tid + 256) * 8;
    ushort_t* lB0 = Bs + tid * 8;
    ushort_t* lB1 = Bs + (tid + 256) * 8;

    f32x4 acc[4][4] = {};

    for (int k0 = 0; k0 < K_; k0 += 32) {
        __syncthreads();                 // previous tile fully consumed
        gload16(ga0 + k0, lA0);
        gload16(ga1 + k0, lA1);
        gload16(gb0 + k0, lB0);
        gload16(gb1 + k0, lB1);
        __syncthreads();                 // drains vmcnt -> tile visible
        bf16x8 af[4], bfr[4];
#pragma unroll
        for (int i = 0; i < 4; i++) {
            af[i]  = *(const bf16x8*)(As + (wm + i * 16 + l16) * 32 + quad * 8);
            bfr[i] = *(const bf16x8*)(Bs + (wn + i * 16 + l16) * 32 + quad * 8);
        }
#pragma unroll
        for (int im = 0; im < 4; im++)
#pragma unroll
            for (int in = 0; in < 4; in++)
                acc[im][in] = __builtin_amdgcn_mfma_f32_16x16x32_bf16(af[im], bfr[in], acc[im][in], 0, 0, 0);
    }

#pragma unroll
    for (int im = 0; im < 4; im++) {
#pragma unroll
        for (int in = 0; in < 4; in++) {
            const int gcol = n0 + wn + in * 16 + l16;     // 0..3071
            const int which = gcol >> 10;                 // 0/1/2
            const int c = gcol & 1023;
            const int h = c >> 6, d = c & 63;
            ushort_t* dst = which == 0 ? q : (which == 1 ? k : v);
#pragma unroll
            for (int r = 0; r < 4; r++) {
                const int grow = m0 + wm + im * 16 + quad * 4 + r;
                if (grow < M_QKV) {
                    const int b = grow / N_;
                    const int nn = grow - b * N_;
                    const ushort_t val = f2bf(acc[im][in][r]);
                    const size_t bh = (size_t)(b * H_ + h);
                    dst[(bh * N_ + nn) * HD + d] = val;
                    if (which == 2)
                        vT[(bh * HD + d) * NT + nn] = val;
                }
            }
        }
    }
}

// ---------------------------------------------------------------------------
// Attention (both paths fused). Block = (qtile, bh). Unchanged from round 5.
// ---------------------------------------------------------------------------
__global__ __launch_bounds__(256, 4)
void attn_kernel(const ushort_t* __restrict__ q, const ushort_t* __restrict__ k,
                 const ushort_t* __restrict__ v, const ushort_t* __restrict__ vT,
                 ushort_t* __restrict__ xvv, ushort_t* __restrict__ xori) {
    __shared__ ushort_t Ks[64][72];
    __shared__ ushort_t Vs[64][72];
    __shared__ ushort_t Vt[64][72];
    __shared__ ushort_t Ps[4][16][72];

    const int tid = threadIdx.x;
    const int wave = tid >> 6, lane = tid & 63;
    const int quad = lane >> 4, l16 = lane & 15;
    const int bh = blockIdx.y;
    const int b = bh >> 4, h = bh & 15;

    const size_t base  = (size_t)bh * N_ * HD;
    const size_t baseT = (size_t)bh * HD * NT;
    const int qr0 = blockIdx.x * 64 + wave * 16;

    bf16x8 qq[2], qv[2];
    {
        const int qrow = qr0 + l16;
#pragma unroll
        for (int kk = 0; kk < 2; kk++) {
            U4 uq, uv; uq.v = make_uint4(0, 0, 0, 0); uv.v = uq.v;
            if (qrow < N_) {
                uq.v = *(const uint4*)(q + base + (size_t)qrow * HD + kk * 32 + quad * 8);
                uv.v = *(const uint4*)(v + base + (size_t)qrow * HD + kk * 32 + quad * 8);
            }
            qq[kk] = *(const bf16x8*)uq.s;
            qv[kk] = *(const bf16x8*)uv.s;
        }
    }

    float l0a[4] = {0.f, 0.f, 0.f, 0.f}, l1a[4] = {0.f, 0.f, 0.f, 0.f};
    f32x4 o0[4] = {}, o1[4] = {};

    const int nkt = (N_ + 63) / 64;  // 17
    for (int kt = 0; kt < nkt; kt++) {
        const int key0 = kt * 64;
        __syncthreads();
#pragma unroll
        for (int i = 0; i < 2; i++) {
            const int c = tid + i * 256;
            const int row = c >> 3;
            const int cc = (c & 7) * 8;
            const int key = key0 + row;
            uint4 kv = make_uint4(0, 0, 0, 0), vv = kv;
            if (key < N_) {
                kv = *(const uint4*)(k + base + (size_t)key * HD + cc);
                vv = *(const uint4*)(v + base + (size_t)key * HD + cc);
            }
            uint4 tv = *(const uint4*)(vT + baseT + (size_t)row * NT + key0 + cc);
            *(uint4*)(&Ks[row][cc]) = kv;
            *(uint4*)(&Vs[row][cc]) = vv;
            *(uint4*)(&Vt[row][cc]) = tv;
        }
        __syncthreads();

#pragma unroll
        for (int path = 0; path < 2; path++) {
            f32x4 s[4];
#pragma unroll
            for (int t = 0; t < 4; t++) {
                const ushort_t (&Kt)[64][72] = (path == 0) ? Ks : Vs;
                bf16x8 b0 = *(const bf16x8*)(&Kt[t * 16 + l16][quad * 8]);
                bf16x8 b1 = *(const bf16x8*)(&Kt[t * 16 + l16][32 + quad * 8]);
                f32x4 a = {};
                a = __builtin_amdgcn_mfma_f32_16x16x32_bf16(path == 0 ? qq[0] : qv[0], b0, a, 0, 0, 0);
                a = __builtin_amdgcn_mfma_f32_16x16x32_bf16(path == 0 ? qq[1] : qv[1], b1, a, 0, 0, 0);
                const int keyg = key0 + t * 16 + l16;
                if (keyg < N_) {
#pragma unroll
                    for (int r = 0; r < 4; r++) s[t][r] = __expf(a[r] * 0.125f);
                } else {
#pragma unroll
                    for (int r = 0; r < 4; r++) s[t][r] = 0.f;
                }
            }

            float* la = (path == 0) ? l0a : l1a;
#pragma unroll
            for (int r = 0; r < 4; r++)
                la[r] += (s[0][r] + s[1][r]) + (s[2][r] + s[3][r]);

#pragma unroll
            for (int t = 0; t < 4; t++)
#pragma unroll
                for (int r = 0; r < 4; r++)
                    Ps[wave][quad * 4 + r][t * 16 + l16] = f2bf_fast(s[t][r]);

            bf16x8 pa0 = *(const bf16x8*)(&Ps[wave][l16][quad * 8]);
            bf16x8 pa1 = *(const bf16x8*)(&Ps[wave][l16][32 + quad * 8]);
#pragma unroll
            for (int t = 0; t < 4; t++) {
                bf16x8 bv0 = *(const bf16x8*)(&Vt[t * 16 + l16][quad * 8]);
                bf16x8 bv1 = *(const bf16x8*)(&Vt[t * 16 + l16][32 + quad * 8]);
                if (path == 0) {
                    o0[t] = __builtin_amdgcn_mfma_f32_16x16x32_bf16(pa0, bv0, o0[t], 0, 0, 0);
                    o0[t] = __builtin_amdgcn_mfma_f32_16x16x32_bf16(pa1, bv1, o0[t], 0, 0, 0);
                } else {
                    o1[t] = __builtin_amdgcn_mfma_f32_16x16x32_bf16(pa0, bv0, o1[t], 0, 0, 0);
                    o1[t] = __builtin_amdgcn_mfma_f32_16x16x32_bf16(pa1, bv1, o1[t], 0, 0, 0);
                }
            }
        }
    }

#pragma unroll
    for (int r = 0; r < 4; r++) {
        float L0 = l0a[r], L1 = l1a[r];
#pragma unroll
        for (int off = 1; off < 16; off <<= 1) {
            L0 += __shfl_xor(L0, off);
            L1 += __shfl_xor(L1, off);
        }
        const int row = qr0 + quad * 4 + r;
        if (row < N_) {
            const float inv0 = 1.0f / L0;
            const float inv1 = 1.0f / L1;
            const size_t rb = (size_t)(b * N_ + row) * C_ + h * HD;
#pragma unroll
            for (int t = 0; t < 4; t++) {
                const int d = t * 16 + l16;
                xori[rb + d] = f2bf(o0[t][r] * inv0);
                xvv[rb + d]  = f2bf(o1[t][r] * inv1);
            }
        }
    }
}

// ---------------------------------------------------------------------------
// GEMM 2 (m97-style): OUT(f32) = Xcat[16400,1024](bf16) * Wbf[1024,1024]^T + bias
// ---------------------------------------------------------------------------
__global__ __launch_bounds__(256)
void gemm_proj(const ushort_t* __restrict__ A, const ushort_t* __restrict__ Bm,
               const float* __restrict__ bias, float* __restrict__ out) {
    __shared__ ushort_t As[128 * 32];
    __shared__ ushort_t Bs[128 * 32];
    const int tid = threadIdx.x;
    const int wave = tid >> 6, lane = tid & 63;
    const int quad = lane >> 4, l16 = lane & 15;
    const int m0 = blockIdx.y * 128, n0 = blockIdx.x * 128;
    const int wm = (wave & 1) * 64, wn = (wave >> 1) * 64;

    const int col8 = (tid & 3) * 8;
    const int row0 = tid >> 2;
    const int ar0 = min(m0 + row0,      M_PROJ - 1);
    const int ar1 = min(m0 + row0 + 64, M_PROJ - 1);
    const ushort_t* ga0 = A + (size_t)ar0 * K_ + col8;
    const ushort_t* ga1 = A + (size_t)ar1 * K_ + col8;
    const ushort_t* gb0 = Bm + (size_t)(n0 + row0) * K_ + col8;
    const ushort_t* gb1 = Bm + (size_t)(n0 + row0 + 64) * K_ + col8;
    ushort_t* lA0 = As + tid * 8;
    ushort_t* lA1 = As + (tid + 256) * 8;
    ushort_t* lB0 = Bs + tid * 8;
    ushort_t* lB1 = Bs + (tid + 256) * 8;

    f32x4 acc[4][4] = {};

    for (int k0 = 0; k0 < K_; k0 += 32) {
        __syncthreads();
        gload16(ga0 + k0, lA0);
        gload16(ga1 + k0, lA1);
        gload16(gb0 + k0, lB0);
        gload16(gb1 + k0, lB1);
        __syncthreads();
        bf16x8 af[4], bfr[4];
#pragma unroll
        for (int i = 0; i < 4; i++) {
            af[i]  = *(const bf16x8*)(As + (wm + i * 16 + l16) * 32 + quad * 8);
            bfr[i] = *(const bf16x8*)(Bs + (wn + i * 16 + l16) * 32 + quad * 8);
        }
#pragma unroll
        for (int im = 0; im < 4; im++)
#pragma unroll
            for (int in = 0; in < 4; in++)
                acc[im][in] = __builtin_amdgcn_mfma_f32_16x16x32_bf16(af[im], bfr[in], acc[im][in], 0, 0, 0);
    }

#pragma unroll
    for (int im = 0; im < 4; im++) {
#pragma unroll
        for (int in = 0; in < 4; in++) {
            const int gcol = n0 + wn + in * 16 + l16;
            const float bb = bias[gcol];
#pragma unroll
            for (int r = 0; r < 4; r++) {
                const int grow = m0 + wm + im * 16 + quad * 4 + r;
                if (grow < M_PROJ)
                    out[(size_t)grow * C_ + gcol] = acc[im][in][r] + bb;
            }
        }
    }
}

// ---------------------------------------------------------------------------
// Memory map (all within proven footprints):
//   d_ws  [0,S1)      : x_bf  (phase 1-2), then xvv  (attn output)  [aliased]
//   d_ws  [S1,2S1)    : xori
//   d_ws  [2S1,3S1)   : v     (phase 2-3), then wproj_bf (1.05M)    [aliased]
//   d_out [0,S1)      : q        (dead before proj writes)
//   d_out [S1,2S1)    : k
//   d_out [2S1,2S1+VT): vT
//   d_out [2S1+VT,..) : wqkv_bf (3.15M)
// ---------------------------------------------------------------------------
extern "C" void kernel_launch(void* const* d_in, const int* in_sizes, int n_in,
                              void* d_out, int out_size, void* d_ws, size_t ws_size,
                              hipStream_t stream) {
    const float* x      = (const float*)d_in[0];
    const float* w_qkv  = (const float*)d_in[1];
    const float* w_proj = (const float*)d_in[2];
    const float* b_proj = (const float*)d_in[3];
    float* out = (float*)d_out;

    ushort_t* ws = (ushort_t*)d_ws;
    ushort_t* x_bf     = ws;                       // aliases xvv
    ushort_t* xvv      = ws;
    ushort_t* xori     = ws + S1;
    ushort_t* v        = ws + 2 * S1;
    ushort_t* wproj_bf = ws + 2 * S1;              // aliases v (converted after attn)

    ushort_t* q        = (ushort_t*)d_out;
    ushort_t* k        = (ushort_t*)d_out + S1;
    ushort_t* vT       = (ushort_t*)d_out + 2 * S1;
    ushort_t* wqkv_bf  = (ushort_t*)d_out + 2 * S1 + VT_SZ;

    // 0) input conversions f32 -> bf16
    {
        const int n8x = (int)(S1 / 8);                 // 1,049,600
        conv_bf16<<<(n8x + 255) / 256, 256, 0, stream>>>(x, x_bf, n8x);
        const int n8w = 3 * C_ * C_ / 8;               // 393,216
        conv_bf16<<<(n8w + 255) / 256, 256, 0, stream>>>(w_qkv, wqkv_bf, n8w);
    }
    // 1) QKV projection (+ vT transposed copy of v)
    {
        dim3 grid(3072 / 128, (M_QKV + 127) / 128);    // 24 x 65
        gemm_qkv<<<grid, 256, 0, stream>>>(x_bf, wqkv_bf, q, k, v, vT);
    }
    // 2) dual attention (x_bf dead; xvv overwrites it)
    {
        dim3 grid((N_ + 63) / 64, B_ * H_);            // 17 x 128
        attn_kernel<<<grid, 256, 0, stream>>>(q, k, v, vT, xvv, xori);
    }
    // 3) w_proj conversion into v's slot (v dead)
    {
        const int n8p = C_ * C_ / 8;                   // 131,072
        conv_bf16<<<(n8p + 255) / 256, 256, 0, stream>>>(w_proj, wproj_bf, n8p);
    }
    // 4) output projection over concatenated [x_new; x_ori]
    {
        dim3 grid(1024 / 128, (M_PROJ + 127) / 128);   // 8 x 129
        gemm_proj<<<grid, 256, 0, stream>>>(xvv, wproj_bf, b_proj, out);
    }
}

// Round 7
// 410.228 us; speedup vs baseline: 1.6775x; 1.0099x over previous
//
#include <hip/hip_runtime.h>

typedef unsigned short ushort_t;
typedef __attribute__((ext_vector_type(8))) __bf16 bf16x8;
typedef __attribute__((ext_vector_type(4))) float f32x4;

constexpr int B_ = 8, N_ = 1025, C_ = 1024, H_ = 16, HD = 64;
constexpr int M_QKV = B_ * N_;          // 8200
constexpr int M_PROJ = 2 * B_ * N_;     // 16400
constexpr int K_ = 1024;
constexpr int NT = 1032;                // vT row stride (16B-aligned)
constexpr size_t S1 = (size_t)B_ * H_ * N_ * HD;    // 8,396,800
constexpr size_t VT_SZ = (size_t)B_ * H_ * HD * NT; // 8,454,144

__device__ __forceinline__ ushort_t f2bf(float f) {
    union { float f; unsigned u; } a; a.f = f;
    unsigned r = a.u + 0x7FFFu + ((a.u >> 16) & 1u);
    return (ushort_t)(r >> 16);
}
__device__ __forceinline__ ushort_t f2bf_fast(float f) {
    return (ushort_t)((__float_as_uint(f) + 0x8000u) >> 16);
}
__device__ __forceinline__ unsigned pk2(float x, float y) {
    unsigned a = __float_as_uint(x) + 0x8000u;
    unsigned b = __float_as_uint(y) + 0x8000u;
    return (a >> 16) | (b & 0xffff0000u);
}
__device__ __forceinline__ uint4 pack8(float4 x, float4 y) {
    return make_uint4(pk2(x.x, x.y), pk2(x.z, x.w), pk2(y.x, y.y), pk2(y.z, y.w));
}

union U4 { uint4 v; ushort_t s[8]; };

__device__ __forceinline__ void gload16(const ushort_t* g, ushort_t* l) {
    __builtin_amdgcn_global_load_lds(
        (const __attribute__((address_space(1))) void*)g,
        (__attribute__((address_space(3))) void*)l, 16, 0, 0);
}

// ---------------------------------------------------------------------------
__global__ __launch_bounds__(256)
void conv_bf16(const float* __restrict__ src, ushort_t* __restrict__ dst, int n8) {
    const int i = blockIdx.x * 256 + threadIdx.x;
    if (i < n8) {
        const float4* s = (const float4*)src + 2 * (size_t)i;
        ((uint4*)dst)[i] = pack8(s[0], s[1]);
    }
}

// ---------------------------------------------------------------------------
// GEMM 1 (m97-style): QKV = Xbf * Wbf^T, 128x128x32 tiles
//   q written PRE-SCALED by 0.125 (exact in bf16); k,v plain; vT transposed v.
// ---------------------------------------------------------------------------
__global__ __launch_bounds__(256)
void gemm_qkv(const ushort_t* __restrict__ A, const ushort_t* __restrict__ Bm,
              ushort_t* __restrict__ q, ushort_t* __restrict__ k,
              ushort_t* __restrict__ v, ushort_t* __restrict__ vT) {
    __shared__ ushort_t As[128 * 32];
    __shared__ ushort_t Bs[128 * 32];
    const int tid = threadIdx.x;
    const int wave = tid >> 6, lane = tid & 63;
    const int quad = lane >> 4, l16 = lane & 15;
    const int m0 = blockIdx.y * 128, n0 = blockIdx.x * 128;
    const int wm = (wave & 1) * 64, wn = (wave >> 1) * 64;

    const int col8 = (tid & 3) * 8;
    const int row0 = tid >> 2;
    const int ar0 = min(m0 + row0,      M_QKV - 1);
    const int ar1 = min(m0 + row0 + 64, M_QKV - 1);
    const ushort_t* ga0 = A + (size_t)ar0 * K_ + col8;
    const ushort_t* ga1 = A + (size_t)ar1 * K_ + col8;
    const ushort_t* gb0 = Bm + (size_t)(n0 + row0) * K_ + col8;
    const ushort_t* gb1 = Bm + (size_t)(n0 + row0 + 64) * K_ + col8;
    ushort_t* lA0 = As + tid * 8;
    ushort_t* lA1 = As + (tid + 256) * 8;
    ushort_t* lB0 = Bs + tid * 8;
    ushort_t* lB1 = Bs + (tid + 256) * 8;

    f32x4 acc[4][4] = {};

    for (int k0 = 0; k0 < K_; k0 += 32) {
        __syncthreads();
        gload16(ga0 + k0, lA0);
        gload16(ga1 + k0, lA1);
        gload16(gb0 + k0, lB0);
        gload16(gb1 + k0, lB1);
        __syncthreads();
        bf16x8 af[4], bfr[4];
#pragma unroll
        for (int i = 0; i < 4; i++) {
            af[i]  = *(const bf16x8*)(As + (wm + i * 16 + l16) * 32 + quad * 8);
            bfr[i] = *(const bf16x8*)(Bs + (wn + i * 16 + l16) * 32 + quad * 8);
        }
#pragma unroll
        for (int im = 0; im < 4; im++)
#pragma unroll
            for (int in = 0; in < 4; in++)
                acc[im][in] = __builtin_amdgcn_mfma_f32_16x16x32_bf16(af[im], bfr[in], acc[im][in], 0, 0, 0);
    }

#pragma unroll
    for (int im = 0; im < 4; im++) {
#pragma unroll
        for (int in = 0; in < 4; in++) {
            const int gcol = n0 + wn + in * 16 + l16;     // 0..3071
            const int which = gcol >> 10;                 // 0/1/2
            const int c = gcol & 1023;
            const int h = c >> 6, d = c & 63;
            ushort_t* dst = which == 0 ? q : (which == 1 ? k : v);
            const float sc = (which == 0) ? 0.125f : 1.0f;  // pre-scale q
#pragma unroll
            for (int r = 0; r < 4; r++) {
                const int grow = m0 + wm + im * 16 + quad * 4 + r;
                if (grow < M_QKV) {
                    const int b = grow / N_;
                    const int nn = grow - b * N_;
                    const ushort_t val = f2bf(acc[im][in][r] * sc);
                    const size_t bh = (size_t)(b * H_ + h);
                    dst[(bh * N_ + nn) * HD + d] = val;
                    if (which == 2)
                        vT[(bh * HD + d) * NT + nn] = val;
                }
            }
        }
    }
}

// ---------------------------------------------------------------------------
// Attention, both paths fused. Block = (qtile, bh).
//   q arrives pre-scaled by 1/8. Ps aliases Ks (safe after barrier 3).
//   Overlapped q-tiles: all rows valid, no row guards. Tail k-tile guarded.
// ---------------------------------------------------------------------------
__global__ __launch_bounds__(256, 4)
void attn_kernel(const ushort_t* __restrict__ q, const ushort_t* __restrict__ k,
                 const ushort_t* __restrict__ v, const ushort_t* __restrict__ vT,
                 ushort_t* __restrict__ xvv, ushort_t* __restrict__ xori) {
    __shared__ ushort_t Ks[64][72];   // K-operand tile; reused as P buffer after barrier 3
    __shared__ ushort_t Vs[64][72];   // v tile [key][dim]
    __shared__ ushort_t Vt[64][72];   // v^T tile [dim][key]

    const int tid = threadIdx.x;
    const int wave = tid >> 6, lane = tid & 63;
    const int quad = lane >> 4, l16 = lane & 15;
    const int bh = blockIdx.y;
    const int b = bh >> 4, h = bh & 15;

    const size_t base  = (size_t)bh * N_ * HD;
    const size_t baseT = (size_t)bh * HD * NT;
    const int qstart = min((int)blockIdx.x * 64, N_ - 64);
    const int qr0 = qstart + wave * 16;

    ushort_t (*Ps)[72] = Ks;          // alias

    // Q fragments (always in-bounds)
    bf16x8 qq[2], qv[2];
    {
        const int qrow = qr0 + l16;
#pragma unroll
        for (int kk = 0; kk < 2; kk++) {
            U4 uq, uv;
            uq.v = *(const uint4*)(q + base + (size_t)qrow * HD + kk * 32 + quad * 8);
            uv.v = *(const uint4*)(v + base + (size_t)qrow * HD + kk * 32 + quad * 8);
            qq[kk] = *(const bf16x8*)uq.s;
            qv[kk] = *(const bf16x8*)uv.s;
        }
    }

    float l0a[4] = {0.f, 0.f, 0.f, 0.f}, l1a[4] = {0.f, 0.f, 0.f, 0.f};
    f32x4 o0[4] = {}, o1[4] = {};

    // staging addresses
    const int srow = tid >> 3;         // 0..31 (i adds 32)
    const int scc  = (tid & 7) * 8;

    const int nkt = (N_ + 63) / 64;   // 17
    for (int kt = 0; kt < nkt; kt++) {
        const int key0 = kt * 64;
        const bool tail = (key0 + 64 > N_);
        __syncthreads();                               // (1) prev tile consumed
        if (!tail) {
#pragma unroll
            for (int i = 0; i < 2; i++) {
                const int row = srow + i * 32;
                const int key = key0 + row;
                uint4 kv = *(const uint4*)(k + base + (size_t)key * HD + scc);
                uint4 vv = *(const uint4*)(v + base + (size_t)key * HD + scc);
                uint4 tv = *(const uint4*)(vT + baseT + (size_t)row * NT + key0 + scc);
                *(uint4*)(&Ks[row][scc]) = kv;
                *(uint4*)(&Vs[row][scc]) = vv;
                *(uint4*)(&Vt[row][scc]) = tv;
            }
        } else {
#pragma unroll
            for (int i = 0; i < 2; i++) {
                const int row = srow + i * 32;
                const int key = key0 + row;
                uint4 kv = make_uint4(0, 0, 0, 0), vv = kv;
                if (key < N_) {
                    kv = *(const uint4*)(k + base + (size_t)key * HD + scc);
                    vv = *(const uint4*)(v + base + (size_t)key * HD + scc);
                }
                uint4 tv = *(const uint4*)(vT + baseT + (size_t)row * NT + key0 + scc);
                *(uint4*)(&Ks[row][scc]) = kv;
                *(uint4*)(&Vs[row][scc]) = vv;
                *(uint4*)(&Vt[row][scc]) = tv;
            }
        }
        __syncthreads();                               // (2) tiles visible

        // ---- path 0: S = (q/8)·k^T ----
        f32x4 s[4];
#pragma unroll
        for (int t = 0; t < 4; t++) {
            bf16x8 b0 = *(const bf16x8*)(&Ks[t * 16 + l16][quad * 8]);
            bf16x8 b1 = *(const bf16x8*)(&Ks[t * 16 + l16][32 + quad * 8]);
            f32x4 a = {};
            a = __builtin_amdgcn_mfma_f32_16x16x32_bf16(qq[0], b0, a, 0, 0, 0);
            a = __builtin_amdgcn_mfma_f32_16x16x32_bf16(qq[1], b1, a, 0, 0, 0);
            s[t] = a;
        }
        __syncthreads();                               // (3) Ks frag reads done -> Ps writable

        if (tail) {
#pragma unroll
            for (int t = 0; t < 4; t++)
                if (key0 + t * 16 + l16 >= N_) {
#pragma unroll
                    for (int r = 0; r < 4; r++) s[t][r] = -1e30f;
                }
        }
#pragma unroll
        for (int t = 0; t < 4; t++)
#pragma unroll
            for (int r = 0; r < 4; r++) {
                const float p = __expf(s[t][r]);
                l0a[r] += p;
                Ps[wave * 16 + quad * 4 + r][t * 16 + l16] = f2bf_fast(p);
            }
        {
            bf16x8 pa0 = *(const bf16x8*)(&Ps[wave * 16 + l16][quad * 8]);
            bf16x8 pa1 = *(const bf16x8*)(&Ps[wave * 16 + l16][32 + quad * 8]);
#pragma unroll
            for (int t = 0; t < 4; t++) {
                bf16x8 bv0 = *(const bf16x8*)(&Vt[t * 16 + l16][quad * 8]);
                bf16x8 bv1 = *(const bf16x8*)(&Vt[t * 16 + l16][32 + quad * 8]);
                o0[t] = __builtin_amdgcn_mfma_f32_16x16x32_bf16(pa0, bv0, o0[t], 0, 0, 0);
                o0[t] = __builtin_amdgcn_mfma_f32_16x16x32_bf16(pa1, bv1, o0[t], 0, 0, 0);
            }
        }

        // ---- path 1: S = v·v^T / 8 ----
#pragma unroll
        for (int t = 0; t < 4; t++) {
            bf16x8 b0 = *(const bf16x8*)(&Vs[t * 16 + l16][quad * 8]);
            bf16x8 b1 = *(const bf16x8*)(&Vs[t * 16 + l16][32 + quad * 8]);
            f32x4 a = {};
            a = __builtin_amdgcn_mfma_f32_16x16x32_bf16(qv[0], b0, a, 0, 0, 0);
            a = __builtin_amdgcn_mfma_f32_16x16x32_bf16(qv[1], b1, a, 0, 0, 0);
            s[t] = a;
        }
        if (tail) {
#pragma unroll
            for (int t = 0; t < 4; t++)
                if (key0 + t * 16 + l16 >= N_) {
#pragma unroll
                    for (int r = 0; r < 4; r++) s[t][r] = -1e30f;
                }
        }
#pragma unroll
        for (int t = 0; t < 4; t++)
#pragma unroll
            for (int r = 0; r < 4; r++) {
                const float p = __expf(s[t][r] * 0.125f);
                l1a[r] += p;
                Ps[wave * 16 + quad * 4 + r][t * 16 + l16] = f2bf_fast(p);
            }
        {
            bf16x8 pa0 = *(const bf16x8*)(&Ps[wave * 16 + l16][quad * 8]);
            bf16x8 pa1 = *(const bf16x8*)(&Ps[wave * 16 + l16][32 + quad * 8]);
#pragma unroll
            for (int t = 0; t < 4; t++) {
                bf16x8 bv0 = *(const bf16x8*)(&Vt[t * 16 + l16][quad * 8]);
                bf16x8 bv1 = *(const bf16x8*)(&Vt[t * 16 + l16][32 + quad * 8]);
                o1[t] = __builtin_amdgcn_mfma_f32_16x16x32_bf16(pa0, bv0, o1[t], 0, 0, 0);
                o1[t] = __builtin_amdgcn_mfma_f32_16x16x32_bf16(pa1, bv1, o1[t], 0, 0, 0);
            }
        }
    }

    // epilogue (all rows valid; overlapped blocks write identical values)
#pragma unroll
    for (int r = 0; r < 4; r++) {
        float L0 = l0a[r], L1 = l1a[r];
#pragma unroll
        for (int off = 1; off < 16; off <<= 1) {
            L0 += __shfl_xor(L0, off);
            L1 += __shfl_xor(L1, off);
        }
        const int row = qr0 + quad * 4 + r;
        const float inv0 = 1.0f / L0;
        const float inv1 = 1.0f / L1;
        const size_t rb = (size_t)(b * N_ + row) * C_ + h * HD;
#pragma unroll
        for (int t = 0; t < 4; t++) {
            const int d = t * 16 + l16;
            xori[rb + d] = f2bf(o0[t][r] * inv0);
            xvv[rb + d]  = f2bf(o1[t][r] * inv1);
        }
    }
}

// ---------------------------------------------------------------------------
// GEMM 2 (m97-style): OUT(f32) = Xcat(bf16) * Wbf^T + bias
// ---------------------------------------------------------------------------
__global__ __launch_bounds__(256)
void gemm_proj(const ushort_t* __restrict__ A, const ushort_t* __restrict__ Bm,
               const float* __restrict__ bias, float* __restrict__ out) {
    __shared__ ushort_t As[128 * 32];
    __shared__ ushort_t Bs[128 * 32];
    const int tid = threadIdx.x;
    const int wave = tid >> 6, lane = tid & 63;
    const int quad = lane >> 4, l16 = lane & 15;
    const int m0 = blockIdx.y * 128, n0 = blockIdx.x * 128;
    const int wm = (wave & 1) * 64, wn = (wave >> 1) * 64;

    const int col8 = (tid & 3) * 8;
    const int row0 = tid >> 2;
    const int ar0 = min(m0 + row0,      M_PROJ - 1);
    const int ar1 = min(m0 + row0 + 64, M_PROJ - 1);
    const ushort_t* ga0 = A + (size_t)ar0 * K_ + col8;
    const ushort_t* ga1 = A + (size_t)ar1 * K_ + col8;
    const ushort_t* gb0 = Bm + (size_t)(n0 + row0) * K_ + col8;
    const ushort_t* gb1 = Bm + (size_t)(n0 + row0 + 64) * K_ + col8;
    ushort_t* lA0 = As + tid * 8;
    ushort_t* lA1 = As + (tid + 256) * 8;
    ushort_t* lB0 = Bs + tid * 8;
    ushort_t* lB1 = Bs + (tid + 256) * 8;

    f32x4 acc[4][4] = {};

    for (int k0 = 0; k0 < K_; k0 += 32) {
        __syncthreads();
        gload16(ga0 + k0, lA0);
        gload16(ga1 + k0, lA1);
        gload16(gb0 + k0, lB0);
        gload16(gb1 + k0, lB1);
        __syncthreads();
        bf16x8 af[4], bfr[4];
#pragma unroll
        for (int i = 0; i < 4; i++) {
            af[i]  = *(const bf16x8*)(As + (wm + i * 16 + l16) * 32 + quad * 8);
            bfr[i] = *(const bf16x8*)(Bs + (wn + i * 16 + l16) * 32 + quad * 8);
        }
#pragma unroll
        for (int im = 0; im < 4; im++)
#pragma unroll
            for (int in = 0; in < 4; in++)
                acc[im][in] = __builtin_amdgcn_mfma_f32_16x16x32_bf16(af[im], bfr[in], acc[im][in], 0, 0, 0);
    }

#pragma unroll
    for (int im = 0; im < 4; im++) {
#pragma unroll
        for (int in = 0; in < 4; in++) {
            const int gcol = n0 + wn + in * 16 + l16;
            const float bb = bias[gcol];
#pragma unroll
            for (int r = 0; r < 4; r++) {
                const int grow = m0 + wm + im * 16 + quad * 4 + r;
                if (grow < M_PROJ)
                    out[(size_t)grow * C_ + gcol] = acc[im][in][r] + bb;
            }
        }
    }
}

// ---------------------------------------------------------------------------
// Memory map:
//   d_ws  [0,S1)      : x_bf (phase 1), then xvv   [aliased]
//   d_ws  [S1,2S1)    : xori
//   d_ws  [2S1,3S1)   : v (phases 1-3), then wproj_bf [aliased, conv after attn]
//   d_out [0,S1)      : q (pre-scaled 1/8)   [dead before proj writes]
//   d_out [S1,2S1)    : k
//   d_out [2S1,2S1+VT): vT
//   d_out [2S1+VT,..) : wqkv_bf
// ---------------------------------------------------------------------------
extern "C" void kernel_launch(void* const* d_in, const int* in_sizes, int n_in,
                              void* d_out, int out_size, void* d_ws, size_t ws_size,
                              hipStream_t stream) {
    const float* x      = (const float*)d_in[0];
    const float* w_qkv  = (const float*)d_in[1];
    const float* w_proj = (const float*)d_in[2];
    const float* b_proj = (const float*)d_in[3];
    float* out = (float*)d_out;

    ushort_t* ws = (ushort_t*)d_ws;
    ushort_t* x_bf     = ws;
    ushort_t* xvv      = ws;
    ushort_t* xori     = ws + S1;
    ushort_t* v        = ws + 2 * S1;
    ushort_t* wproj_bf = ws + 2 * S1;

    ushort_t* q        = (ushort_t*)d_out;
    ushort_t* k        = (ushort_t*)d_out + S1;
    ushort_t* vT       = (ushort_t*)d_out + 2 * S1;
    ushort_t* wqkv_bf  = (ushort_t*)d_out + 2 * S1 + VT_SZ;

    {
        const int n8x = (int)(S1 / 8);
        conv_bf16<<<(n8x + 255) / 256, 256, 0, stream>>>(x, x_bf, n8x);
        const int n8w = 3 * C_ * C_ / 8;
        conv_bf16<<<(n8w + 255) / 256, 256, 0, stream>>>(w_qkv, wqkv_bf, n8w);
    }
    {
        dim3 grid(3072 / 128, (M_QKV + 127) / 128);    // 24 x 65
        gemm_qkv<<<grid, 256, 0, stream>>>(x_bf, wqkv_bf, q, k, v, vT);
    }
    {
        dim3 grid((N_ + 63) / 64, B_ * H_);            // 17 x 128
        attn_kernel<<<grid, 256, 0, stream>>>(q, k, v, vT, xvv, xori);
    }
    {
        const int n8p = C_ * C_ / 8;
        conv_bf16<<<(n8p + 255) / 256, 256, 0, stream>>>(w_proj, wproj_bf, n8p);
    }
    {
        dim3 grid(1024 / 128, (M_PROJ + 127) / 128);   // 8 x 129
        gemm_proj<<<grid, 256, 0, stream>>>(xvv, wproj_bf, b_proj, out);
    }
}